// Round 11
// baseline (109.294 us; speedup 1.0000x reference)
//
#include <hip/hip_runtime.h>
#include <stdint.h>

typedef unsigned long long u64;
typedef unsigned int u32;

#define R_N 1000
#define K_N 80
#define NCOL 81           // K_N + 1 (background col)
#define TOPK_N 100
#define OUT_W 87          // 4 box + 1 score + 1 cls + 81 full scores
#define IMG_W_ 1333.0f
#define IMG_H_ 800.0f
#define CSTR 100          // per-class cand slots (first 100 kept per class provably suffice)
#define SHI 101           // padded u32 stride for khi: 101%32=5, gcd(5,32)=1 -> all banks cycle
#define NQUAD ((R_N * NCOL) / 4)
#define NMAX 448          // fast-path NMS cap
#define WMAX 7
#define KM (K_N * CSTR)   // 8000 fixed candidate slots
#define POISON 0xAAAAAAAAu  // harness re-poisons d_ws to 0xAA before every launch

__device__ __forceinline__ u32 f32_order(float f) {
    u32 u = __float_as_uint(f);
    return u ^ (((u32)((int)u >> 31)) | 0x80000000u);
}
__device__ __forceinline__ float f32_unorder(u32 o) {
    u32 u = (o & 0x80000000u) ? (o ^ 0x80000000u) : ~o;
    return __uint_as_float(u);
}

// software grid barrier, self-cleaning, load-first CAS (R6/R9/R10-validated).
__device__ __forceinline__ void grid_barrier(u32* bar, u32 nblk) {
    __syncthreads();
    if (threadIdx.x == 0) {
        __threadfence();   // release prior global writes
        if (__hip_atomic_load(bar, __ATOMIC_RELAXED, __HIP_MEMORY_SCOPE_AGENT) == POISON)
            atomicCAS(bar, POISON, 0u);   // exactly one success; value then stays in [0, nblk]
        __hip_atomic_fetch_add(bar, 1u, __ATOMIC_ACQ_REL, __HIP_MEMORY_SCOPE_AGENT);
        while (__hip_atomic_load(bar, __ATOMIC_ACQUIRE, __HIP_MEMORY_SCOPE_AGENT) < nblk)
            __builtin_amdgcn_s_sleep(2);
    }
    __syncthreads();
}

struct P2 {                       // per-class NMS scratch
    float4 bx4[R_N];
    u64 key_s[R_N];
    u64 pool[NMAX * WMAX];        // ukey pre-sort / Mrow bitmatrix / keep[] fallback
    float area[R_N];
    float sc[R_N];                // staged score column (survives both NMS passes)
    u64 keep_words[16];
};
struct P3 {                       // distributed top-100 scratch (every block)
    u32 khi[K_N * SHI];           // high 32b of all 8000 keys, padded stride 101 (b32 searches)
    u32 klo_own[CSTR];            // low 32b of OWN class keys (tie compare + reconstruction)
    int rnk[TOPK_N];
    u64 wx[TOPK_N];               // winner keys
    int wr[TOPK_N];               // winner ranks
    int wn;
};
union SMEM { P2 p2; P3 p3; };

__global__ __launch_bounds__(256, 1) void k_all(const float* __restrict__ boxes,
                                                const float* __restrict__ scores,
                                                float* __restrict__ hdr,
                                                u32* __restrict__ bars,
                                                u64* __restrict__ cand,
                                                float* __restrict__ outp) {
    __shared__ SMEM sm;
    __shared__ float s_sum[4], s_max[4];
    __shared__ int s_cnt[4], s_wcnt[4], s_kb[2];
    __shared__ float s_thres;

    const int bid = blockIdx.x, tid = threadIdx.x;
    const int lane = tid & 63, wv = tid >> 6;
    const int c = bid;
    const u64 below = (lane == 0) ? 0ull : (~0ull >> (64 - lane));

    // ---- stage score column c (scattered; overlaps stats below) ----
    for (int r = tid; r < R_N; r += 256) sm.p2.sc[r] = scores[r * NCOL + c];

    // ---- stats partial (sum,max of fg scores over this block's quad slice) ----
    {
        float sum = 0.f, mx = -1e30f;
        int q = bid * 256 + tid;               // 80*256 = 20480 >= 20250 quads
        if (q < NQUAD) {
            float4 v = ((const float4*)scores)[q];
            int m = (q * 4) % NCOL;
            float vv[4] = {v.x, v.y, v.z, v.w};
#pragma unroll
            for (int e = 0; e < 4; ++e) {
                int mm = m + e; if (mm >= NCOL) mm -= NCOL;
                if (mm != K_N) { sum += vv[e]; mx = fmaxf(mx, vv[e]); }
            }
        }
#pragma unroll
        for (int off = 32; off > 0; off >>= 1) {
            sum += __shfl_down(sum, off);
            mx = fmaxf(mx, __shfl_down(mx, off));
        }
        if (lane == 0) { s_sum[wv] = sum; s_max[wv] = mx; }
        __syncthreads();                       // also publishes sc[] for the NMS pass
        if (tid == 0) {
            hdr[2 * bid] = s_sum[0] + s_sum[1] + s_sum[2] + s_sum[3];
            hdr[2 * bid + 1] = fmaxf(fmaxf(s_max[0], s_max[1]), fmaxf(s_max[2], s_max[3]));
        }
    }

    // ---- NMS: speculative pass at th=0.05 (exact in practice), redo if verification fails ----
    float th = 0.05f;
    for (int pass = 0; ; ++pass) {
        // 4-wave ballot compaction: wave wv covers rows [wv*256, wv*256+256)
        u64* ukey = sm.p2.pool;
        {
            u64 m[4]; int wcnt = 0;
#pragma unroll
            for (int k = 0; k < 4; ++k) {
                int r = wv * 256 + k * 64 + lane;
                bool pred = (r < R_N) && (sm.p2.sc[r] > th);
                m[k] = __ballot(pred);
                wcnt += __popcll(m[k]);
            }
            if (lane == 0) s_wcnt[wv] = wcnt;
            __syncthreads();
            int run = 0;
            for (int w2 = 0; w2 < wv; ++w2) run += s_wcnt[w2];
#pragma unroll
            for (int k = 0; k < 4; ++k) {
                int r = wv * 256 + k * 64 + lane;
                bool pred = (r < R_N) && (sm.p2.sc[r] > th);
                if (pred) {
                    int slot = run + __popcll(m[k] & below);
                    ukey[slot] = ((u64)f32_order(sm.p2.sc[r]) << 32) | (u64)(u32)(R_N - 1 - r);
                }
                run += __popcll(m[k]);
            }
        }
        __syncthreads();
        const int n = s_wcnt[0] + s_wcnt[1] + s_wcnt[2] + s_wcnt[3];

        // counting-rank sort + clipped box gather (all 256 threads)
        for (int j = tid; j < n; j += 256) {
            u64 kj = ukey[j];
            int rank = 0;
            for (int k = 0; k < n; ++k) rank += (ukey[k] > kj) ? 1 : 0;
            int r = (R_N - 1) - (int)(kj & 0xFFFFFFFFull);
            float4 b = ((const float4*)boxes)[r * K_N + c];
            float x1 = fminf(fmaxf(b.x, 0.f), IMG_W_);
            float y1 = fminf(fmaxf(b.y, 0.f), IMG_H_);
            float x2 = fminf(fmaxf(b.z, 0.f), IMG_W_);
            float y2 = fminf(fmaxf(b.w, 0.f), IMG_H_);
            sm.p2.key_s[rank] = kj;
            sm.p2.bx4[rank] = make_float4(x1, y1, x2, y2);
            sm.p2.area[rank] = fmaxf(x2 - x1, 0.f) * fmaxf(y2 - y1, 0.f);
        }
        __syncthreads();

        if (n <= NMAX) {
            // suppression bit-matrix: (w, i-quarter) tasks spread over all 4 waves
            const int W = (n + 63) >> 6;
            u64* Mrow = sm.p2.pool;            // ukey dead after sort
            const int q1 = n >> 2, q2 = n >> 1, q3 = (3 * n) >> 2;
            for (int t2 = wv; t2 < 4 * W; t2 += 4) {
                int w = t2 >> 2, qh = t2 & 3;
                int i0 = (qh == 0) ? 0 : (qh == 1) ? q1 : (qh == 2) ? q2 : q3;
                int i1 = (qh == 0) ? q1 : (qh == 1) ? q2 : (qh == 2) ? q3 : n;
                int j = w * 64 + lane;
                bool jv = j < n;
                float4 bj = jv ? sm.p2.bx4[j] : make_float4(0.f, 0.f, 0.f, 0.f);
                float aj = jv ? sm.p2.area[j] : 0.f;
                for (int i = i0; i < i1; ++i) {
                    float4 bi = sm.p2.bx4[i];
                    float ai = sm.p2.area[i];
                    float xx1 = fmaxf(bi.x, bj.x), yy1 = fmaxf(bi.y, bj.y);
                    float xx2 = fminf(bi.z, bj.z), yy2 = fminf(bi.w, bj.w);
                    float inter = fmaxf(xx2 - xx1, 0.f) * fmaxf(yy2 - yy1, 0.f);
                    bool sup = jv && (j > i) &&
                               (inter / fmaxf(ai + aj - inter, 1e-9f) > 0.5f);
                    u64 m = __ballot(sup);
                    if (lane == 0) Mrow[i * W + w] = m;
                }
            }
            __syncthreads();

            if (wv == 0) {
                u64 keep_w = 0;
                if (lane < W) {
                    int rem = n - lane * 64;
                    keep_w = (rem >= 64) ? ~0ull : ((1ull << rem) - 1ull);
                }
                const int lw = (lane < W) ? lane : 0;
                u64 fifo[8];
#pragma unroll
                for (int d = 0; d < 8; ++d) fifo[d] = (d < n) ? Mrow[d * W + lw] : 0ull;
                for (int ib = 0; ib < n; ib += 8) {
#pragma unroll
                    for (int d = 0; d < 8; ++d) {
                        int i = ib + d;
                        if (i >= n) break;
                        u64 row = fifo[d];
                        int ip = i + 8;
                        fifo[d] = (ip < n) ? Mrow[ip * W + lw] : 0ull;
                        u64 kw = __shfl(keep_w, i >> 6);
                        if ((kw >> (i & 63)) & 1ull) keep_w &= ~row;
                    }
                }
                if (lane < W) sm.p2.keep_words[lane] = keep_w;
                if (lane >= W && lane < 16) sm.p2.keep_words[lane] = 0;
            }
        } else {
            // fallback: block-wide serial greedy (cold; correctness only)
            int* keep = (int*)sm.p2.pool;
            for (int j = tid; j < n; j += 256) keep[j] = 1;
            __syncthreads();
            for (int i = 0; i < n - 1; ++i) {
                __syncthreads();
                if (!keep[i]) continue;
                float4 bi = sm.p2.bx4[i];
                float ai = sm.p2.area[i];
                for (int j = i + 1 + tid; j < n; j += 256) {
                    if (!keep[j]) continue;
                    float xx1 = fmaxf(bi.x, sm.p2.bx4[j].x), yy1 = fmaxf(bi.y, sm.p2.bx4[j].y);
                    float xx2 = fminf(bi.z, sm.p2.bx4[j].z), yy2 = fminf(bi.w, sm.p2.bx4[j].w);
                    float inter = fmaxf(xx2 - xx1, 0.f) * fmaxf(yy2 - yy1, 0.f);
                    if (inter / fmaxf(ai + sm.p2.area[j] - inter, 1e-9f) > 0.5f) keep[j] = 0;
                }
            }
            __syncthreads();
            if (wv == 0) {
                for (int w = 0; w < 16; ++w) {
                    int j = w * 64 + lane;
                    u64 m = __ballot((j < n) && keep[j]);
                    if (lane == 0) sm.p2.keep_words[w] = m;
                }
            }
        }
        __syncthreads();

        // emit first <=100 kept per class, zero-pad remaining slots
        if (wv == 0) {
            int kb = 0;
            for (int j0 = 0; j0 < n; j0 += 64) {
                int j = j0 + lane;
                u64 mw = sm.p2.keep_words[j0 >> 6];
                bool kp = (j < n) && ((mw >> lane) & 1ull);
                u64 mm = __ballot(kp);
                int kr = kb + __popcll(mm & below);
                if (kp && kr < CSTR) {
                    u64 kj = sm.p2.key_s[j];
                    u32 osc = (u32)(kj >> 32);
                    int rr = (R_N - 1) - (int)(kj & 0xFFFFFFFFull);
                    int flat = c * R_N + j;
                    cand[c * CSTR + kr] =
                        ((u64)osc << 27) | ((u64)(u32)(131071 - flat) << 10) | (u64)(u32)rr;
                }
                kb += __popcll(mm);
            }
            if (kb > CSTR) kb = CSTR;
            for (int k2 = kb + lane; k2 < CSTR; k2 += 64) cand[c * CSTR + k2] = 0;
        }

        if (pass == 0) {
            grid_barrier(&bars[0], K_N);
            // exact threshold from all 80 partials (wave-parallel, identical per block)
            if (wv == 0) {
                float S = hdr[2 * lane], M = hdr[2 * lane + 1];
                if (lane + 64 < K_N) {
                    S += hdr[2 * (lane + 64)];
                    M = fmaxf(M, hdr[2 * (lane + 64) + 1]);
                }
#pragma unroll
                for (int off = 32; off > 0; off >>= 1) {
                    S += __shfl_down(S, off);
                    M = fmaxf(M, __shfl_down(M, off));
                }
                if (lane == 0)
                    s_thres = fminf(0.05f, 0.5f * (S / (float)(R_N * K_N) + M));
            }
            __syncthreads();
            if (s_thres == 0.05f) break;       // hot path: speculation was exact
            th = s_thres;                      // cold: redo with the true threshold
        } else {
            grid_barrier(&bars[1], K_N);
            break;
        }
    }

    // ---- phase 3 (ALL blocks): b32 hi-word searches over sparse tasks ----
    {
        // stage khi of all 8000 keys (padded stride) + klo of own class; count nonzero
        const ulonglong2* cp = (const ulonglong2*)cand;
        int cnt = 0;
        for (int t = tid; t < KM / 2; t += 256) {
            ulonglong2 v = cp[t];
            int e0 = 2 * t;
            int cc = e0 / CSTR, pos = e0 - cc * CSTR;
            sm.p3.khi[cc * SHI + pos] = (u32)(v.x >> 32);
            sm.p3.khi[cc * SHI + pos + 1] = (u32)(v.y >> 32);
            if (cc == c) {
                sm.p3.klo_own[pos] = (u32)v.x;
                sm.p3.klo_own[pos + 1] = (u32)v.y;
            }
            cnt += (v.x != 0ull) + (v.y != 0ull);
        }
        if (tid < K_N) sm.p3.khi[tid * SHI + CSTR] = 0;   // pad slot: safe converged reads
#pragma unroll
        for (int off = 32; off > 0; off >>= 1) cnt += __shfl_down(cnt, off);
        if (lane == 0) s_cnt[wv] = cnt;
        if (tid < TOPK_N) sm.p3.rnk[tid] = tid;   // own-class contribution = sorted position
        if (tid == 0) sm.p3.wn = 0;
        __syncthreads();
        const int total = s_cnt[0] + s_cnt[1] + s_cnt[2] + s_cnt[3];
        const int target = total < TOPK_N ? total : TOPK_N;

        // own kept count kb (nonzero prefix of own list; khi!=0 iff key!=0)
        if (wv < 2) {
            int t = wv * 64 + lane;
            bool nz = (t < CSTR) && (sm.p3.khi[c * SHI + t] != 0);
            u64 m = __ballot(nz);
            if (lane == 0) s_kb[wv] = __popcll(m);
        }
        __syncthreads();
        const int kb = s_kb[0] + s_kb[1];

        // kb*79 tasks; 8 task-states/thread, dual b32 searches (count > and count >=)
        const int TASKS = kb * (K_N - 1);
        const int NG = (TASKS + 2047) / 2048;
        for (int g = 0; g < NG; ++g) {
            int lo1[8], hi1[8], lo2[8], hi2[8], base[8], cbase[8], ii[8];
            u32 xhi[8], xlo[8];
            bool act[8];
#pragma unroll
            for (int s = 0; s < 8; ++s) {
                int t = g * 2048 + s * 256 + tid;   // consecutive lanes -> consecutive cc
                act[s] = t < TASKS;
                int i = act[s] ? (t / (K_N - 1)) : 0;
                int cc = act[s] ? (t - i * (K_N - 1)) : 0;
                cc += (cc >= c);                    // skip own class
                ii[s] = i;
                base[s] = cc * SHI;
                cbase[s] = cc * CSTR;
                xhi[s] = sm.p3.khi[c * SHI + i];
                xlo[s] = sm.p3.klo_own[i];
                lo1[s] = 0; hi1[s] = CSTR;
                lo2[s] = 0; hi2[s] = CSTR;
            }
#pragma unroll
            for (int st = 0; st < 7; ++st) {        // 7 steps close a length-100 interval
#pragma unroll
                for (int s = 0; s < 8; ++s) {
                    int m1 = (lo1[s] + hi1[s]) >> 1;
                    u32 v1 = sm.p3.khi[base[s] + m1];
                    bool l1 = lo1[s] < hi1[s];
                    bool g1 = l1 && (v1 > xhi[s]);
                    lo1[s] = g1 ? m1 + 1 : lo1[s];
                    hi1[s] = (l1 && !g1) ? m1 : hi1[s];
                    int m2 = (lo2[s] + hi2[s]) >> 1;
                    u32 v2 = sm.p3.khi[base[s] + m2];
                    bool l2 = lo2[s] < hi2[s];
                    bool g2 = l2 && (v2 >= xhi[s]);
                    lo2[s] = g2 ? m2 + 1 : lo2[s];
                    hi2[s] = (l2 && !g2) ? m2 : hi2[s];
                }
            }
#pragma unroll
            for (int s = 0; s < 8; ++s) {
                if (!act[s]) continue;
                int add = lo1[s];
                // tie range [lo1, lo2): khi equal; compare low words from L2 (rare)
                for (int j = lo1[s]; j < lo2[s]; ++j)
                    add += ((u32)cand[cbase[s] + j] > xlo[s]) ? 1 : 0;
                if (add > 0) atomicAdd(&sm.p3.rnk[ii[s]], add);
            }
        }
        __syncthreads();

        // collect winners (rank < target) into LDS
        if (tid < kb) {
            int r = sm.p3.rnk[tid];
            if (r < target) {
                int idx = atomicAdd(&sm.p3.wn, 1);
                sm.p3.wx[idx] = ((u64)sm.p3.khi[c * SHI + tid] << 32) | (u64)sm.p3.klo_own[tid];
                sm.p3.wr[idx] = r;
            }
        }
        __syncthreads();
        const int wn = sm.p3.wn;

        // cooperative element-parallel row writes (ranks unique -> race-free)
        for (int e = tid; e < wn * OUT_W; e += 256) {
            int w = e / OUT_W, col = e - w * OUT_W;
            u64 x = sm.p3.wx[w];
            int r = sm.p3.wr[w];
            int prop = (int)(x & 0x3FFull);
            float val;
            if (col < 4) {
                float b = boxes[prop * (K_N * 4) + c * 4 + col];
                float lim = (col & 1) ? IMG_H_ : IMG_W_;
                val = fminf(fmaxf(b, 0.f), lim);
            } else if (col == 4) {
                val = f32_unorder((u32)((x >> 27) & 0xFFFFFFFFull));
            } else if (col == 5) {
                val = (float)c;
            } else {
                val = scores[prop * NCOL + (col - 6)];
            }
            outp[r * OUT_W + col] = val;
        }
        // zero tail rows [target, 100), block-strided (disjoint from winner rows)
        for (int row = target + bid; row < TOPK_N; row += K_N) {
            int ob = row * OUT_W;
            for (int e = tid; e < OUT_W; e += 256) outp[ob + e] = 0.f;
        }
    }
}

extern "C" void kernel_launch(void* const* d_in, const int* in_sizes, int n_in,
                              void* d_out, int out_size, void* d_ws, size_t ws_size,
                              hipStream_t stream) {
    const float* boxes = (const float*)d_in[0];
    const float* scores = (const float*)d_in[1];
    float* hdr = (float*)d_ws;                     // 160 f32 partials at [0, 640)
    u32* bars = (u32*)((char*)d_ws + 768);         // 2 self-cleaning barrier counters
    u64* cand = (u64*)((char*)d_ws + 1024);        // 8000 u64 candidate slots

    k_all<<<dim3(K_N), dim3(256), 0, stream>>>(boxes, scores, hdr, bars, cand, (float*)d_out);
}

// Round 12
// 101.743 us; speedup vs baseline: 1.0742x; 1.0742x over previous
//
#include <hip/hip_runtime.h>
#include <stdint.h>

typedef unsigned long long u64;
typedef unsigned int u32;

#define R_N 1000
#define K_N 80
#define NCOL 81           // K_N + 1 (background col)
#define TOPK_N 100
#define OUT_W 87          // 4 box + 1 score + 1 cls + 81 full scores
#define IMG_W_ 1333.0f
#define IMG_H_ 800.0f
#define CSTR 100          // per-class cand slots (first 100 kept per class provably suffice)
#define CSTRP 101         // padded LDS stride: 101%16=5 coprime w/ 16 bank-pairs
#define NQUAD ((R_N * NCOL) / 4)
#define NMAX 448          // fast-path NMS cap
#define WMAX 7
#define KM (K_N * CSTR)   // 8000 fixed candidate slots
#define POISON 0xAAAAAAAAu  // harness re-poisons d_ws to 0xAA before every launch

__device__ __forceinline__ u32 f32_order(float f) {
    u32 u = __float_as_uint(f);
    return u ^ (((u32)((int)u >> 31)) | 0x80000000u);
}
__device__ __forceinline__ float f32_unorder(u32 o) {
    u32 u = (o & 0x80000000u) ? (o ^ 0x80000000u) : ~o;
    return __uint_as_float(u);
}

// software grid barrier, self-cleaning, load-first CAS (R6/R9/R10-validated).
__device__ __forceinline__ void grid_barrier(u32* bar, u32 nblk) {
    __syncthreads();
    if (threadIdx.x == 0) {
        __threadfence();   // release prior global writes
        if (__hip_atomic_load(bar, __ATOMIC_RELAXED, __HIP_MEMORY_SCOPE_AGENT) == POISON)
            atomicCAS(bar, POISON, 0u);   // exactly one success; value then stays in [0, nblk]
        __hip_atomic_fetch_add(bar, 1u, __ATOMIC_ACQ_REL, __HIP_MEMORY_SCOPE_AGENT);
        while (__hip_atomic_load(bar, __ATOMIC_ACQUIRE, __HIP_MEMORY_SCOPE_AGENT) < nblk)
            __builtin_amdgcn_s_sleep(2);
    }
    __syncthreads();
}

struct P2 {                       // per-class NMS scratch
    float4 bx4[R_N];
    u64 key_s[R_N];
    u64 pool[NMAX * WMAX];        // ukey pre-sort / Mrow bitmatrix / keep[] fallback
    float area[R_N];
    float sc[R_N];                // staged score column (survives both NMS passes)
    u64 keep_words[16];
    int s_n;
};
struct P3 {                       // distributed top-100 scratch (every block)
    u64 keys[K_N * CSTRP];        // all 8000 keys, class stride padded to 101
    int rnk[TOPK_N];
};
union SMEM { P2 p2; P3 p3; };

__global__ __launch_bounds__(256, 1) void k_all(const float* __restrict__ boxes,
                                                const float* __restrict__ scores,
                                                float* __restrict__ hdr,
                                                u32* __restrict__ bars,
                                                u64* __restrict__ cand,
                                                float* __restrict__ outp) {
    __shared__ SMEM sm;
    __shared__ float s_sum[4], s_max[4];
    __shared__ int s_cnt[4], s_kb[2];
    __shared__ float s_thres;

    const int bid = blockIdx.x, tid = threadIdx.x;
    const int lane = tid & 63, wv = tid >> 6;
    const int c = bid;
    const u64 below = (lane == 0) ? 0ull : (~0ull >> (64 - lane));

    // ---- stage score column c (scattered; overlaps stats below) ----
    for (int r = tid; r < R_N; r += 256) sm.p2.sc[r] = scores[r * NCOL + c];

    // ---- stats partial (sum,max of fg scores over this block's quad slice) ----
    {
        float sum = 0.f, mx = -1e30f;
        int q = bid * 256 + tid;               // 80*256 = 20480 >= 20250 quads
        if (q < NQUAD) {
            float4 v = ((const float4*)scores)[q];
            int m = (q * 4) % NCOL;
            float vv[4] = {v.x, v.y, v.z, v.w};
#pragma unroll
            for (int e = 0; e < 4; ++e) {
                int mm = m + e; if (mm >= NCOL) mm -= NCOL;
                if (mm != K_N) { sum += vv[e]; mx = fmaxf(mx, vv[e]); }
            }
        }
#pragma unroll
        for (int off = 32; off > 0; off >>= 1) {
            sum += __shfl_down(sum, off);
            mx = fmaxf(mx, __shfl_down(mx, off));
        }
        if (lane == 0) { s_sum[wv] = sum; s_max[wv] = mx; }
        __syncthreads();                       // also publishes sc[] for the NMS pass
        if (tid == 0) {
            hdr[2 * bid] = s_sum[0] + s_sum[1] + s_sum[2] + s_sum[3];
            hdr[2 * bid + 1] = fmaxf(fmaxf(s_max[0], s_max[1]), fmaxf(s_max[2], s_max[3]));
        }
    }

    // ---- NMS: speculative pass at th=0.05 (exact in practice), redo if verification fails ----
    float th = 0.05f;
    for (int pass = 0; ; ++pass) {
        // compact valid (sc > th); key = (score desc, orig idx asc) — wave 0 only
        u64* ukey = sm.p2.pool;
        if (wv == 0) {
            int nn = 0;
            for (int r0 = 0; r0 < R_N; r0 += 64) {
                int r = r0 + lane;
                bool pred = (r < R_N) && (sm.p2.sc[r] > th);
                u64 m = __ballot(pred);
                if (pred) {
                    int slot = nn + __popcll(m & below);
                    ukey[slot] = ((u64)f32_order(sm.p2.sc[r]) << 32) | (u64)(u32)(R_N - 1 - r);
                }
                nn += __popcll(m);
            }
            if (lane == 0) sm.p2.s_n = nn;
        }
        __syncthreads();
        const int n = sm.p2.s_n;

        // counting-rank sort + clipped box gather (all 256 threads)
        for (int j = tid; j < n; j += 256) {
            u64 kj = ukey[j];
            int rank = 0;
            for (int k = 0; k < n; ++k) rank += (ukey[k] > kj) ? 1 : 0;
            int r = (R_N - 1) - (int)(kj & 0xFFFFFFFFull);
            float4 b = ((const float4*)boxes)[r * K_N + c];
            float x1 = fminf(fmaxf(b.x, 0.f), IMG_W_);
            float y1 = fminf(fmaxf(b.y, 0.f), IMG_H_);
            float x2 = fminf(fmaxf(b.z, 0.f), IMG_W_);
            float y2 = fminf(fmaxf(b.w, 0.f), IMG_H_);
            sm.p2.key_s[rank] = kj;
            sm.p2.bx4[rank] = make_float4(x1, y1, x2, y2);
            sm.p2.area[rank] = fmaxf(x2 - x1, 0.f) * fmaxf(y2 - y1, 0.f);
        }
        __syncthreads();

        if (n <= NMAX) {
            // suppression bit-matrix: tasks (w, i-half) spread over all 4 waves
            const int W = (n + 63) >> 6;
            u64* Mrow = sm.p2.pool;            // ukey dead after sort
            const int nh = n >> 1;
            for (int t2 = wv; t2 < 2 * W; t2 += 4) {
                int w = t2 >> 1, ih = t2 & 1;
                int i0 = ih ? nh : 0;
                int i1 = ih ? n : nh;
                int j = w * 64 + lane;
                bool jv = j < n;
                float4 bj = jv ? sm.p2.bx4[j] : make_float4(0.f, 0.f, 0.f, 0.f);
                float aj = jv ? sm.p2.area[j] : 0.f;
                for (int i = i0; i < i1; ++i) {
                    float4 bi = sm.p2.bx4[i];
                    float ai = sm.p2.area[i];
                    float xx1 = fmaxf(bi.x, bj.x), yy1 = fmaxf(bi.y, bj.y);
                    float xx2 = fminf(bi.z, bj.z), yy2 = fminf(bi.w, bj.w);
                    float inter = fmaxf(xx2 - xx1, 0.f) * fmaxf(yy2 - yy1, 0.f);
                    bool sup = jv && (j > i) &&
                               (inter / fmaxf(ai + aj - inter, 1e-9f) > 0.5f);
                    u64 m = __ballot(sup);
                    if (lane == 0) Mrow[i * W + w] = m;
                }
            }
            __syncthreads();

            if (wv == 0) {
                u64 keep_w = 0;
                if (lane < W) {
                    int rem = n - lane * 64;
                    keep_w = (rem >= 64) ? ~0ull : ((1ull << rem) - 1ull);
                }
                const int lw = (lane < W) ? lane : 0;
                u64 fifo[8];
#pragma unroll
                for (int d = 0; d < 8; ++d) fifo[d] = (d < n) ? Mrow[d * W + lw] : 0ull;
                for (int ib = 0; ib < n; ib += 8) {
#pragma unroll
                    for (int d = 0; d < 8; ++d) {
                        int i = ib + d;
                        if (i >= n) break;
                        u64 row = fifo[d];
                        int ip = i + 8;
                        fifo[d] = (ip < n) ? Mrow[ip * W + lw] : 0ull;
                        u64 kw = __shfl(keep_w, i >> 6);
                        if ((kw >> (i & 63)) & 1ull) keep_w &= ~row;
                    }
                }
                if (lane < W) sm.p2.keep_words[lane] = keep_w;
                if (lane >= W && lane < 16) sm.p2.keep_words[lane] = 0;
            }
        } else {
            // fallback: block-wide serial greedy (cold; correctness only)
            int* keep = (int*)sm.p2.pool;
            for (int j = tid; j < n; j += 256) keep[j] = 1;
            __syncthreads();
            for (int i = 0; i < n - 1; ++i) {
                __syncthreads();
                if (!keep[i]) continue;
                float4 bi = sm.p2.bx4[i];
                float ai = sm.p2.area[i];
                for (int j = i + 1 + tid; j < n; j += 256) {
                    if (!keep[j]) continue;
                    float xx1 = fmaxf(bi.x, sm.p2.bx4[j].x), yy1 = fmaxf(bi.y, sm.p2.bx4[j].y);
                    float xx2 = fminf(bi.z, sm.p2.bx4[j].z), yy2 = fminf(bi.w, sm.p2.bx4[j].w);
                    float inter = fmaxf(xx2 - xx1, 0.f) * fmaxf(yy2 - yy1, 0.f);
                    if (inter / fmaxf(ai + sm.p2.area[j] - inter, 1e-9f) > 0.5f) keep[j] = 0;
                }
            }
            __syncthreads();
            if (wv == 0) {
                for (int w = 0; w < 16; ++w) {
                    int j = w * 64 + lane;
                    u64 m = __ballot((j < n) && keep[j]);
                    if (lane == 0) sm.p2.keep_words[w] = m;
                }
            }
        }
        __syncthreads();

        // emit first <=100 kept per class, zero-pad remaining slots
        if (wv == 0) {
            int kb = 0;
            for (int j0 = 0; j0 < n; j0 += 64) {
                int j = j0 + lane;
                u64 mw = sm.p2.keep_words[j0 >> 6];
                bool kp = (j < n) && ((mw >> lane) & 1ull);
                u64 mm = __ballot(kp);
                int kr = kb + __popcll(mm & below);
                if (kp && kr < CSTR) {
                    u64 kj = sm.p2.key_s[j];
                    u32 osc = (u32)(kj >> 32);
                    int rr = (R_N - 1) - (int)(kj & 0xFFFFFFFFull);
                    int flat = c * R_N + j;
                    cand[c * CSTR + kr] =
                        ((u64)osc << 27) | ((u64)(u32)(131071 - flat) << 10) | (u64)(u32)rr;
                }
                kb += __popcll(mm);
            }
            if (kb > CSTR) kb = CSTR;
            for (int k2 = kb + lane; k2 < CSTR; k2 += 64) cand[c * CSTR + k2] = 0;
        }

        if (pass == 0) {
            grid_barrier(&bars[0], K_N);
            // exact threshold from all 80 partials (wave-parallel, identical per block)
            if (wv == 0) {
                float S = hdr[2 * lane], M = hdr[2 * lane + 1];
                if (lane + 64 < K_N) {
                    S += hdr[2 * (lane + 64)];
                    M = fmaxf(M, hdr[2 * (lane + 64) + 1]);
                }
#pragma unroll
                for (int off = 32; off > 0; off >>= 1) {
                    S += __shfl_down(S, off);
                    M = fmaxf(M, __shfl_down(M, off));
                }
                if (lane == 0)
                    s_thres = fminf(0.05f, 0.5f * (S / (float)(R_N * K_N) + M));
            }
            __syncthreads();
            if (s_thres == 0.05f) break;       // hot path: speculation was exact
            th = s_thres;                      // cold: redo with the true threshold
        } else {
            grid_barrier(&bars[1], K_N);
            break;
        }
    }

    // ---- phase 3 (ALL blocks): stage keys (padded stride) -> rank own candidates ----
    {
        // stage 8000 keys into padded layout (pairs never straddle a class: 100 is even)
        const ulonglong2* cp = (const ulonglong2*)cand;
        int cnt = 0;
        for (int t = tid; t < KM / 2; t += 256) {
            ulonglong2 v = cp[t];
            int e0 = 2 * t;
            int cc = e0 / CSTR, pos = e0 - cc * CSTR;
            sm.p3.keys[cc * CSTRP + pos] = v.x;
            sm.p3.keys[cc * CSTRP + pos + 1] = v.y;
            cnt += (v.x != 0ull) + (v.y != 0ull);
        }
#pragma unroll
        for (int off = 32; off > 0; off >>= 1) cnt += __shfl_down(cnt, off);
        if (lane == 0) s_cnt[wv] = cnt;
        if (tid < TOPK_N) sm.p3.rnk[tid] = tid;   // own-class contribution = sorted position
        __syncthreads();
        const int total = s_cnt[0] + s_cnt[1] + s_cnt[2] + s_cnt[3];
        const int target = total < TOPK_N ? total : TOPK_N;

        // own kept count kb (nonzero prefix of own list)
        if (wv < 2) {
            int t = wv * 64 + lane;
            bool nz = (t < CSTR) && (sm.p3.keys[c * CSTRP + t] != 0ull);
            u64 m = __ballot(nz);
            if (lane == 0) s_kb[wv] = __popcll(m);
        }
        __syncthreads();
        const int kb = s_kb[0] + s_kb[1];

        // kb*79 tasks (own-cand i x 79 OTHER class lists); i = t % kb -> consecutive
        // lanes hit DISTINCT rnk[i] (de-serialized atomics); 8 interleaved searches/thread
        const int TASKS = kb * (K_N - 1);
        for (int g = 0; g * 2048 < TASKS; ++g) {
            int lo[8], hi[8], ii[8], base[8];
            u64 xv[8];
            bool act[8];
#pragma unroll
            for (int s = 0; s < 8; ++s) {
                int t = g * 2048 + s * 256 + tid;
                act[s] = t < TASKS;
                int i = 0, cc = 0;
                if (act[s]) { i = t % kb; cc = t / kb; }
                cc += (cc >= c);               // skip own class
                ii[s] = i;
                base[s] = cc * CSTRP;
                xv[s] = sm.p3.keys[c * CSTRP + i];
                if (xv[s] == 0ull) act[s] = false;
                lo[s] = 0; hi[s] = CSTR;
            }
#pragma unroll
            for (int st = 0; st < 7; ++st) {   // 7 steps close a length-100 interval
#pragma unroll
                for (int s = 0; s < 8; ++s) {
                    int mid = (lo[s] + hi[s]) >> 1;
                    u64 v = sm.p3.keys[base[s] + mid];
                    bool live = lo[s] < hi[s];
                    bool gt = live && (v > xv[s]);
                    lo[s] = gt ? mid + 1 : lo[s];
                    hi[s] = (live && !gt) ? mid : hi[s];
                }
            }
#pragma unroll
            for (int s = 0; s < 8; ++s)
                if (act[s] && lo[s] > 0) atomicAdd(&sm.p3.rnk[ii[s]], lo[s]);
        }
        __syncthreads();

        // winners write their full output row (ranks are unique -> race-free)
        if (tid < CSTR) {
            u64 x = sm.p3.keys[c * CSTRP + tid];
            int r = sm.p3.rnk[tid];
            if (x != 0ull && r < target) {
                int prop = (int)(x & 0x3FFull);
                float score = f32_unorder((u32)((x >> 27) & 0xFFFFFFFFull));
                int ob = r * OUT_W;
                float4 bx = ((const float4*)boxes)[prop * K_N + c];
                outp[ob + 0] = fminf(fmaxf(bx.x, 0.f), IMG_W_);
                outp[ob + 1] = fminf(fmaxf(bx.y, 0.f), IMG_H_);
                outp[ob + 2] = fminf(fmaxf(bx.z, 0.f), IMG_W_);
                outp[ob + 3] = fminf(fmaxf(bx.w, 0.f), IMG_H_);
                outp[ob + 4] = score;
                outp[ob + 5] = (float)c;
                const int sb = prop * NCOL;
#pragma unroll 9
                for (int j = 0; j < NCOL; ++j) outp[ob + 6 + j] = scores[sb + j];
            }
        }
        // zero tail rows [target, 100), block-strided (disjoint from winner rows)
        for (int row = target + bid; row < TOPK_N; row += K_N) {
            int ob = row * OUT_W;
            for (int e = tid; e < OUT_W; e += 256) outp[ob + e] = 0.f;
        }
    }
}

extern "C" void kernel_launch(void* const* d_in, const int* in_sizes, int n_in,
                              void* d_out, int out_size, void* d_ws, size_t ws_size,
                              hipStream_t stream) {
    const float* boxes = (const float*)d_in[0];
    const float* scores = (const float*)d_in[1];
    float* hdr = (float*)d_ws;                     // 160 f32 partials at [0, 640)
    u32* bars = (u32*)((char*)d_ws + 768);         // 2 self-cleaning barrier counters
    u64* cand = (u64*)((char*)d_ws + 1024);        // 8000 u64 candidate slots

    k_all<<<dim3(K_N), dim3(256), 0, stream>>>(boxes, scores, hdr, bars, cand, (float*)d_out);
}

// Round 13
// 100.577 us; speedup vs baseline: 1.0867x; 1.0116x over previous
//
#include <hip/hip_runtime.h>
#include <stdint.h>

typedef unsigned long long u64;
typedef unsigned int u32;

#define R_N 1000
#define K_N 80
#define NCOL 81           // K_N + 1 (background col)
#define TOPK_N 100
#define OUT_W 87          // 4 box + 1 score + 1 cls + 81 full scores
#define IMG_W_ 1333.0f
#define IMG_H_ 800.0f
#define CSTR 100          // per-class cand slots (first 100 kept per class provably suffice)
#define CSTRP 101         // padded LDS stride: 101%16=5 coprime w/ 16 bank-pairs
#define NQUAD ((R_N * NCOL) / 4)
#define NMAX 448          // fast-path NMS cap
#define WMAX 7
#define KM (K_N * CSTR)   // 8000 fixed candidate slots
#define POISON 0xAAAAAAAAu  // harness re-poisons d_ws to 0xAA before every launch

__device__ __forceinline__ u32 f32_order(float f) {
    u32 u = __float_as_uint(f);
    return u ^ (((u32)((int)u >> 31)) | 0x80000000u);
}
__device__ __forceinline__ float f32_unorder(u32 o) {
    u32 u = (o & 0x80000000u) ? (o ^ 0x80000000u) : ~o;
    return __uint_as_float(u);
}

// software grid barrier, self-cleaning, load-first CAS (R6/R10/R12-validated).
__device__ __forceinline__ void grid_barrier(u32* bar, u32 nblk) {
    __syncthreads();
    if (threadIdx.x == 0) {
        __threadfence();   // release prior global writes
        if (__hip_atomic_load(bar, __ATOMIC_RELAXED, __HIP_MEMORY_SCOPE_AGENT) == POISON)
            atomicCAS(bar, POISON, 0u);   // exactly one success; value then stays in [0, nblk]
        __hip_atomic_fetch_add(bar, 1u, __ATOMIC_ACQ_REL, __HIP_MEMORY_SCOPE_AGENT);
        while (__hip_atomic_load(bar, __ATOMIC_ACQUIRE, __HIP_MEMORY_SCOPE_AGENT) < nblk)
            __builtin_amdgcn_s_sleep(2);
    }
    __syncthreads();
}

struct P2 {                       // per-class NMS scratch (sc[] lives OUTSIDE the union)
    float4 bx4[R_N];
    u64 key_s[R_N];
    u64 pool[NMAX * WMAX];        // ukey pre-sort / Mrow bitmatrix / keep[] fallback
    float area[R_N];
    u64 keep_words[16];
    int s_n;
};
struct P3 {                       // distributed top-100 scratch (every block)
    u64 keys[K_N * CSTRP];        // all 8000 keys, class stride padded to 101
    int rnk[TOPK_N];              // beyond P2 extent -> never aliases NMS state
    u64 wx[TOPK_N];
    int wr[TOPK_N];
    int wn;
};
union SMEM { P2 p2; P3 p3; };

__global__ __launch_bounds__(256, 1) void k_all(const float* __restrict__ boxes,
                                                const float* __restrict__ scores,
                                                float* __restrict__ hdr,
                                                u32* __restrict__ bars,
                                                u64* __restrict__ cand,
                                                float* __restrict__ outp) {
    __shared__ SMEM sm;
    __shared__ float sc[R_N];     // staged score column, survives speculative-redo + staging
    __shared__ float s_sum[4], s_max[4];
    __shared__ int s_cnt[4], s_kb[2];
    __shared__ float s_thres;

    const int bid = blockIdx.x, tid = threadIdx.x;
    const int lane = tid & 63, wv = tid >> 6;
    const int c = bid;
    const u64 below = (lane == 0) ? 0ull : (~0ull >> (64 - lane));

    // ---- stage score column c (scattered; overlaps stats below) ----
    for (int r = tid; r < R_N; r += 256) sc[r] = scores[r * NCOL + c];

    // ---- stats partial (sum,max of fg scores over this block's quad slice) ----
    {
        float sum = 0.f, mx = -1e30f;
        int q = bid * 256 + tid;               // 80*256 = 20480 >= 20250 quads
        if (q < NQUAD) {
            float4 v = ((const float4*)scores)[q];
            int m = (q * 4) % NCOL;
            float vv[4] = {v.x, v.y, v.z, v.w};
#pragma unroll
            for (int e = 0; e < 4; ++e) {
                int mm = m + e; if (mm >= NCOL) mm -= NCOL;
                if (mm != K_N) { sum += vv[e]; mx = fmaxf(mx, vv[e]); }
            }
        }
#pragma unroll
        for (int off = 32; off > 0; off >>= 1) {
            sum += __shfl_down(sum, off);
            mx = fmaxf(mx, __shfl_down(mx, off));
        }
        if (lane == 0) { s_sum[wv] = sum; s_max[wv] = mx; }
        __syncthreads();                       // also publishes sc[] for the NMS pass
        if (tid == 0) {
            hdr[2 * bid] = s_sum[0] + s_sum[1] + s_sum[2] + s_sum[3];
            hdr[2 * bid + 1] = fmaxf(fmaxf(s_max[0], s_max[1]), fmaxf(s_max[2], s_max[3]));
        }
    }

    // ---- NMS: speculative pass at th=0.05 (exact in practice), redo if verification fails ----
    float th = 0.05f;
    for (int pass = 0; ; ++pass) {
        // compact valid (sc > th); key = (score desc, orig idx asc) — wave 0 only
        u64* ukey = sm.p2.pool;
        if (wv == 0) {
            int nn = 0;
            for (int r0 = 0; r0 < R_N; r0 += 64) {
                int r = r0 + lane;
                bool pred = (r < R_N) && (sc[r] > th);
                u64 m = __ballot(pred);
                if (pred) {
                    int slot = nn + __popcll(m & below);
                    ukey[slot] = ((u64)f32_order(sc[r]) << 32) | (u64)(u32)(R_N - 1 - r);
                }
                nn += __popcll(m);
            }
            if (lane == 0) sm.p2.s_n = nn;
        }
        __syncthreads();
        const int n = sm.p2.s_n;

        // counting-rank sort + clipped box gather (all 256 threads)
        for (int j = tid; j < n; j += 256) {
            u64 kj = ukey[j];
            int rank = 0;
            for (int k = 0; k < n; ++k) rank += (ukey[k] > kj) ? 1 : 0;
            int r = (R_N - 1) - (int)(kj & 0xFFFFFFFFull);
            float4 b = ((const float4*)boxes)[r * K_N + c];
            float x1 = fminf(fmaxf(b.x, 0.f), IMG_W_);
            float y1 = fminf(fmaxf(b.y, 0.f), IMG_H_);
            float x2 = fminf(fmaxf(b.z, 0.f), IMG_W_);
            float y2 = fminf(fmaxf(b.w, 0.f), IMG_H_);
            sm.p2.key_s[rank] = kj;
            sm.p2.bx4[rank] = make_float4(x1, y1, x2, y2);
            sm.p2.area[rank] = fmaxf(x2 - x1, 0.f) * fmaxf(y2 - y1, 0.f);
        }
        __syncthreads();

        if (n <= NMAX) {
            // suppression bit-matrix: tasks (w, i-half) spread over all 4 waves
            const int W = (n + 63) >> 6;
            u64* Mrow = sm.p2.pool;            // ukey dead after sort
            const int nh = n >> 1;
            for (int t2 = wv; t2 < 2 * W; t2 += 4) {
                int w = t2 >> 1, ih = t2 & 1;
                int i0 = ih ? nh : 0;
                int i1 = ih ? n : nh;
                int j = w * 64 + lane;
                bool jv = j < n;
                float4 bj = jv ? sm.p2.bx4[j] : make_float4(0.f, 0.f, 0.f, 0.f);
                float aj = jv ? sm.p2.area[j] : 0.f;
                for (int i = i0; i < i1; ++i) {
                    float4 bi = sm.p2.bx4[i];
                    float ai = sm.p2.area[i];
                    float xx1 = fmaxf(bi.x, bj.x), yy1 = fmaxf(bi.y, bj.y);
                    float xx2 = fminf(bi.z, bj.z), yy2 = fminf(bi.w, bj.w);
                    float inter = fmaxf(xx2 - xx1, 0.f) * fmaxf(yy2 - yy1, 0.f);
                    bool sup = jv && (j > i) &&
                               (inter / fmaxf(ai + aj - inter, 1e-9f) > 0.5f);
                    u64 m = __ballot(sup);
                    if (lane == 0) Mrow[i * W + w] = m;
                }
            }
            __syncthreads();

            if (wv == 0) {
                u64 keep_w = 0;
                if (lane < W) {
                    int rem = n - lane * 64;
                    keep_w = (rem >= 64) ? ~0ull : ((1ull << rem) - 1ull);
                }
                const int lw = (lane < W) ? lane : 0;
                u64 fifo[8];
#pragma unroll
                for (int d = 0; d < 8; ++d) fifo[d] = (d < n) ? Mrow[d * W + lw] : 0ull;
                for (int ib = 0; ib < n; ib += 8) {
#pragma unroll
                    for (int d = 0; d < 8; ++d) {
                        int i = ib + d;
                        if (i >= n) break;
                        u64 row = fifo[d];
                        int ip = i + 8;
                        fifo[d] = (ip < n) ? Mrow[ip * W + lw] : 0ull;
                        u64 kw = __shfl(keep_w, i >> 6);
                        if ((kw >> (i & 63)) & 1ull) keep_w &= ~row;
                    }
                }
                if (lane < W) sm.p2.keep_words[lane] = keep_w;
                if (lane >= W && lane < 16) sm.p2.keep_words[lane] = 0;
            }
        } else {
            // fallback: block-wide serial greedy (cold; correctness only)
            int* keep = (int*)sm.p2.pool;
            for (int j = tid; j < n; j += 256) keep[j] = 1;
            __syncthreads();
            for (int i = 0; i < n - 1; ++i) {
                __syncthreads();
                if (!keep[i]) continue;
                float4 bi = sm.p2.bx4[i];
                float ai = sm.p2.area[i];
                for (int j = i + 1 + tid; j < n; j += 256) {
                    if (!keep[j]) continue;
                    float xx1 = fmaxf(bi.x, sm.p2.bx4[j].x), yy1 = fmaxf(bi.y, sm.p2.bx4[j].y);
                    float xx2 = fminf(bi.z, sm.p2.bx4[j].z), yy2 = fminf(bi.w, sm.p2.bx4[j].w);
                    float inter = fmaxf(xx2 - xx1, 0.f) * fmaxf(yy2 - yy1, 0.f);
                    if (inter / fmaxf(ai + sm.p2.area[j] - inter, 1e-9f) > 0.5f) keep[j] = 0;
                }
            }
            __syncthreads();
            if (wv == 0) {
                for (int w = 0; w < 16; ++w) {
                    int j = w * 64 + lane;
                    u64 m = __ballot((j < n) && keep[j]);
                    if (lane == 0) sm.p2.keep_words[w] = m;
                }
            }
        }
        __syncthreads();

        // emit first <=100 kept per class, zero-pad remaining slots
        if (wv == 0) {
            int kb = 0;
            for (int j0 = 0; j0 < n; j0 += 64) {
                int j = j0 + lane;
                u64 mw = sm.p2.keep_words[j0 >> 6];
                bool kp = (j < n) && ((mw >> lane) & 1ull);
                u64 mm = __ballot(kp);
                int kr = kb + __popcll(mm & below);
                if (kp && kr < CSTR) {
                    u64 kj = sm.p2.key_s[j];
                    u32 osc = (u32)(kj >> 32);
                    int rr = (R_N - 1) - (int)(kj & 0xFFFFFFFFull);
                    int flat = c * R_N + j;
                    cand[c * CSTR + kr] =
                        ((u64)osc << 27) | ((u64)(u32)(131071 - flat) << 10) | (u64)(u32)rr;
                }
                kb += __popcll(mm);
            }
            if (kb > CSTR) kb = CSTR;
            for (int k2 = kb + lane; k2 < CSTR; k2 += 64) cand[c * CSTR + k2] = 0;
        }

        grid_barrier(&bars[pass], K_N);

        // stage all 8000 keys (padded stride) + count nonzero — issued BEFORE the
        // threshold check so the 16 coalesced load rounds overlap the wv0 reduction.
        // Safe on the cold path: sc[] is outside the union; stale keys re-staged here.
        {
            const ulonglong2* cp = (const ulonglong2*)cand;
            int cnt = 0;
            for (int t = tid; t < KM / 2; t += 256) {
                ulonglong2 v = cp[t];
                int e0 = 2 * t;
                int cc2 = e0 / CSTR, pos = e0 - cc2 * CSTR;
                sm.p3.keys[cc2 * CSTRP + pos] = v.x;
                sm.p3.keys[cc2 * CSTRP + pos + 1] = v.y;
                cnt += (v.x != 0ull) + (v.y != 0ull);
            }
#pragma unroll
            for (int off = 32; off > 0; off >>= 1) cnt += __shfl_down(cnt, off);
            if (lane == 0) s_cnt[wv] = cnt;
        }

        if (pass == 0) {
            // exact threshold from all 80 partials (wv0; loads overlap staging in flight)
            if (wv == 0) {
                float S = hdr[2 * lane], M = hdr[2 * lane + 1];
                if (lane + 64 < K_N) {
                    S += hdr[2 * (lane + 64)];
                    M = fmaxf(M, hdr[2 * (lane + 64) + 1]);
                }
#pragma unroll
                for (int off = 32; off > 0; off >>= 1) {
                    S += __shfl_down(S, off);
                    M = fmaxf(M, __shfl_down(M, off));
                }
                if (lane == 0)
                    s_thres = fminf(0.05f, 0.5f * (S / (float)(R_N * K_N) + M));
            }
            __syncthreads();
            if (s_thres == 0.05f) break;       // hot path: speculation was exact
            th = s_thres;                      // cold: redo with the true threshold
        } else break;
    }

    // ---- phase 3 (ALL blocks): rank own candidates via interleaved binary searches ----
    {
        __syncthreads();                       // keys + s_cnt published
        const int total = s_cnt[0] + s_cnt[1] + s_cnt[2] + s_cnt[3];
        const int target = total < TOPK_N ? total : TOPK_N;

        if (tid < TOPK_N) sm.p3.rnk[tid] = tid;   // own-class contribution = sorted position
        if (tid == 0) sm.p3.wn = 0;
        // own kept count kb (nonzero prefix of own list)
        if (wv < 2) {
            int t = wv * 64 + lane;
            bool nz = (t < CSTR) && (sm.p3.keys[c * CSTRP + t] != 0ull);
            u64 m = __ballot(nz);
            if (lane == 0) s_kb[wv] = __popcll(m);
        }
        __syncthreads();
        const int kb = s_kb[0] + s_kb[1];

        // kb*79 tasks (own-cand i x 79 OTHER class lists); i = t % kb -> consecutive
        // lanes hit DISTINCT rnk[i] (de-serialized atomics); 8 interleaved searches/thread
        const int TASKS = kb * (K_N - 1);
        for (int g = 0; g * 2048 < TASKS; ++g) {
            int lo[8], hi[8], ii[8], base[8];
            u64 xv[8];
            bool act[8];
#pragma unroll
            for (int s = 0; s < 8; ++s) {
                int t = g * 2048 + s * 256 + tid;
                act[s] = t < TASKS;
                int i = 0, cc2 = 0;
                if (act[s]) { i = t % kb; cc2 = t / kb; }
                cc2 += (cc2 >= c);             // skip own class
                ii[s] = i;
                base[s] = cc2 * CSTRP;
                xv[s] = sm.p3.keys[c * CSTRP + i];
                if (xv[s] == 0ull) act[s] = false;
                lo[s] = 0; hi[s] = CSTR;
            }
#pragma unroll
            for (int st = 0; st < 7; ++st) {   // 7 steps close a length-100 interval
#pragma unroll
                for (int s = 0; s < 8; ++s) {
                    int mid = (lo[s] + hi[s]) >> 1;
                    u64 v = sm.p3.keys[base[s] + mid];
                    bool live = lo[s] < hi[s];
                    bool gt = live && (v > xv[s]);
                    lo[s] = gt ? mid + 1 : lo[s];
                    hi[s] = (live && !gt) ? mid : hi[s];
                }
            }
#pragma unroll
            for (int s = 0; s < 8; ++s)
                if (act[s] && lo[s] > 0) atomicAdd(&sm.p3.rnk[ii[s]], lo[s]);
        }
        __syncthreads();

        // collect winners (rank < target) into LDS
        if (tid < kb) {
            int r = sm.p3.rnk[tid];
            if (r < target) {
                int idx = atomicAdd(&sm.p3.wn, 1);
                sm.p3.wx[idx] = sm.p3.keys[c * CSTRP + tid];
                sm.p3.wr[idx] = r;
            }
        }
        __syncthreads();
        const int wn = sm.p3.wn;

        // cooperative element-parallel row writes (ranks unique -> race-free)
        for (int e = tid; e < wn * OUT_W; e += 256) {
            int w = e / OUT_W, col = e - w * OUT_W;
            u64 x = sm.p3.wx[w];
            int r = sm.p3.wr[w];
            int prop = (int)(x & 0x3FFull);
            float val;
            if (col < 4) {
                float b = boxes[prop * (K_N * 4) + c * 4 + col];
                float lim = (col & 1) ? IMG_H_ : IMG_W_;
                val = fminf(fmaxf(b, 0.f), lim);
            } else if (col == 4) {
                val = f32_unorder((u32)((x >> 27) & 0xFFFFFFFFull));
            } else if (col == 5) {
                val = (float)c;
            } else {
                val = scores[prop * NCOL + (col - 6)];
            }
            outp[r * OUT_W + col] = val;
        }
        // zero tail rows [target, 100), block-strided (disjoint from winner rows)
        for (int row = target + bid; row < TOPK_N; row += K_N) {
            int ob = row * OUT_W;
            for (int e = tid; e < OUT_W; e += 256) outp[ob + e] = 0.f;
        }
    }
}

extern "C" void kernel_launch(void* const* d_in, const int* in_sizes, int n_in,
                              void* d_out, int out_size, void* d_ws, size_t ws_size,
                              hipStream_t stream) {
    const float* boxes = (const float*)d_in[0];
    const float* scores = (const float*)d_in[1];
    float* hdr = (float*)d_ws;                     // 160 f32 partials at [0, 640)
    u32* bars = (u32*)((char*)d_ws + 768);         // 2 self-cleaning barrier counters
    u64* cand = (u64*)((char*)d_ws + 1024);        // 8000 u64 candidate slots

    k_all<<<dim3(K_N), dim3(256), 0, stream>>>(boxes, scores, hdr, bars, cand, (float*)d_out);
}